// Round 1
// baseline (376.771 us; speedup 1.0000x reference)
//
#include <hip/hip_runtime.h>

// ---------------------------------------------------------------------------
// SNN Perceptron Equalizer (LIF recurrent net), MI355X
//
// Key identities exploited:
//  * xt[b,t,j] = emb[x[b, (164t+j)>>7], (164t+j)&127]  -> per t only 2..3
//    distinct features f contribute, so xt @ W_in^T collapses to a sum of
//    2..3 precomputed partial dots P[t][seg][symbol][h].
//  * z is binary & sparse  -> z @ W_rec^T done as sparse column gather of
//    a pre-transposed W_rec (WT[h][j]).
//  * z_sum[b,:] = 32*b_out + sum_h count[b,h] * W_out[:,h]
//  * spikerate = total_spikes / 2^25 (exact fp32)
// ---------------------------------------------------------------------------

#define T_STEPS 32
#define FDIM    41
#define HDIM    256
#define ODIM    16
#define BDIM    4096
#define MF      164
#define NB      16   // batch elements per block in main kernel

// workspace layout (floats): P[32*3*16*256], WT[256*256], then int counter
#define P_FLOATS  (32 * 3 * 16 * 256)
#define WT_FLOATS (256 * 256)

// ---------------------------------------------------------------------------
// K1: build P table (fp64 accum), transpose W_rec, zero spike counter
// grid = 1536 (P) + 256 (transpose) blocks, 256 threads
// ---------------------------------------------------------------------------
__global__ __launch_bounds__(256) void k_prep(const float* __restrict__ emb,
                                              const float* __restrict__ W_in,
                                              const float* __restrict__ W_rec,
                                              float* __restrict__ P,
                                              float* __restrict__ WT,
                                              int* __restrict__ counter)
{
    const int bid = blockIdx.x;
    const int tid = threadIdx.x;

    if (bid < 1536) {
        // one block per (t, seg, symbol); thread = h
        const int t  = bid / 48;
        const int r  = bid % 48;
        const int si = r / 16;
        const int s  = r % 16;

        const int k0   = t * MF;
        const int f    = (k0 >> 7) + si;
        const int base = f << 7;
        const int c0   = max(k0, base) - base;
        const int c1   = min(k0 + MF, base + 128) - base;
        const int j0   = max(k0, base) - k0;

        double acc = 0.0;
        for (int u = 0; u < c1 - c0; ++u) {
            acc += (double)emb[(s << 7) + c0 + u] *
                   (double)W_in[tid * MF + j0 + u];
        }
        P[((t * 3 + si) * 16 + s) * 256 + tid] = (float)acc;
    } else {
        // transpose W_rec: WT[h][j] = W_rec[j][h]
        const int h = bid - 1536;
        WT[h * 256 + tid] = W_rec[tid * 256 + h];
        if (h == 0 && tid == 0) *counter = 0;
    }
}

// ---------------------------------------------------------------------------
// K2: main LIF scan. grid = BDIM/NB = 256 blocks, 256 threads (thread = h).
// Each block owns NB batch elements; v,i state in registers (unrolled arrays).
// ---------------------------------------------------------------------------
__global__ __launch_bounds__(256) void k_main(const int* __restrict__ x,
                                              const float* __restrict__ P,
                                              const float* __restrict__ WT,
                                              const float* __restrict__ W_out,
                                              const float* __restrict__ b_out,
                                              float* __restrict__ out,
                                              int* __restrict__ counter)
{
#pragma clang fp contract(off)
    __shared__ __align__(16) float P_lds[3 * 16 * 256];   // 48 KB
    __shared__ float Wout_lds[16 * 257];                  // padded, 16.4 KB
    __shared__ int   xs[NB * FDIM];
    __shared__ unsigned long long zmask[2][NB][4];        // double buffered
    __shared__ unsigned char cnt[256 * NB];               // [h][bl]
    __shared__ int red[256];

    const int tid  = threadIdx.x;
    const int b0   = blockIdx.x * NB;
    const int wave = tid >> 6;
    const int lane = tid & 63;

    // stage symbols for this block's batch elements (coalesced)
    for (int idx = tid; idx < NB * FDIM; idx += 256)
        xs[idx] = x[b0 * FDIM + idx];
    // stage W_out with +1 padded stride (bank-conflict-free epilogue)
    for (int idx = tid; idx < 16 * 256; idx += 256)
        Wout_lds[(idx >> 8) * 257 + (idx & 255)] = W_out[idx];
    // zero spike counts
    for (int bl = 0; bl < NB; ++bl)
        cnt[tid * NB + bl] = 0;
    // zero initial spike masks (z0 = 0)
    if (tid < NB * 4)
        zmask[0][tid >> 2][tid & 3] = 0ULL;

    float v[NB], cur[NB];
    #pragma unroll
    for (int bl = 0; bl < NB; ++bl) { v[bl] = 0.0f; cur[bl] = 0.0f; }
    int myspk = 0;

    __syncthreads();

    for (int t = 0; t < T_STEPS; ++t) {
        const int k0 = t * MF;
        const int f0 = k0 >> 7;
        const int ns = ((k0 + MF - 1) >> 7) - f0 + 1;   // 2 or 3 segments

        // stage this timestep's P slab into LDS (contiguous, float4)
        const float4* src = (const float4*)(P + (size_t)t * (3 * 16 * 256));
        const int n4 = ns * 16 * 64;
        for (int idx = tid; idx < n4; idx += 256)
            ((float4*)P_lds)[idx] = src[idx];
        __syncthreads();

        const int rb = t & 1, wb = rb ^ 1;

        #pragma unroll
        for (int bl = 0; bl < NB; ++bl) {
            // sparse recurrent term from PREVIOUS step's spikes
            float rec = 0.0f;
            #pragma unroll
            for (int w = 0; w < 4; ++w) {
                unsigned long long m = zmask[rb][bl][w];
                while (m) {                       // uniform across block
                    const int b = __builtin_ctzll(m);
                    m &= m - 1;
                    rec += WT[((w << 6) + b) * 256 + tid];  // coalesced 1KB row
                }
            }

            // feedforward: 2..3 table lookups
            const int s0 = xs[bl * FDIM + f0];
            const int s1 = xs[bl * FDIM + f0 + 1];
            float ff = P_lds[(0 * 16 + s0) * 256 + tid]
                     + P_lds[(1 * 16 + s1) * 256 + tid];
            if (ns == 3) {
                const int s2 = xs[bl * FDIM + f0 + 2];
                ff += P_lds[(2 * 16 + s2) * 256 + tid];
            }

            // LIF dynamics (fp32, no contraction; matches reference ordering)
            const float vd = v[bl] + 0.1f * (cur[bl] - v[bl]);
            const float id = cur[bl] * 0.8f;
            const bool  z  = (vd - 1.0f) > 0.0f;
            v[bl]   = z ? 0.0f : vd;
            cur[bl] = (id + ff) + rec;

            if (z) { cnt[tid * NB + bl]++; myspk++; }
            const unsigned long long bal = __ballot(z ? 1 : 0);
            if (lane == 0) zmask[wb][bl][wave] = bal;
        }
        __syncthreads();   // protects P_lds overwrite & publishes zmask
    }

    // --- total spike count (integer, deterministic) ---
    red[tid] = myspk;
    __syncthreads();
    for (int s = 128; s > 0; s >>= 1) {
        if (tid < s) red[tid] += red[tid + s];
        __syncthreads();
    }
    if (tid == 0) atomicAdd(counter, red[0]);

    // --- epilogue: z_sum[b,o] = 32*b_out[o] + sum_h cnt[b,h]*W_out[o,h] ---
    const int bl = tid >> 4;
    const int o  = tid & 15;
    float acc = 32.0f * b_out[o];
    for (int h = 0; h < 256; ++h)
        acc += (float)cnt[h * NB + bl] * Wout_lds[o * 257 + h];
    out[(b0 + bl) * ODIM + o] = acc;   // contiguous per block -> coalesced
}

// ---------------------------------------------------------------------------
// K3: spikerate = count / 2^25 (exact in fp32 since count < 2^24)
// ---------------------------------------------------------------------------
__global__ void k_fin(const int* __restrict__ counter, float* __restrict__ out)
{
    out[BDIM * ODIM] = (float)(*counter) * (1.0f / 33554432.0f);
}

// ---------------------------------------------------------------------------
extern "C" void kernel_launch(void* const* d_in, const int* in_sizes, int n_in,
                              void* d_out, int out_size, void* d_ws, size_t ws_size,
                              hipStream_t stream)
{
    const int*   x     = (const int*)  d_in[0];
    const float* emb   = (const float*)d_in[1];
    const float* W_in  = (const float*)d_in[2];
    const float* W_rec = (const float*)d_in[3];
    const float* W_out = (const float*)d_in[4];
    const float* b_out = (const float*)d_in[5];
    float* out = (float*)d_out;

    float* P       = (float*)d_ws;
    float* WT      = P + P_FLOATS;
    int*   counter = (int*)(WT + WT_FLOATS);

    k_prep<<<1536 + 256, 256, 0, stream>>>(emb, W_in, W_rec, P, WT, counter);
    k_main<<<BDIM / NB, 256, 0, stream>>>(x, P, WT, W_out, b_out, out, counter);
    k_fin<<<1, 1, 0, stream>>>(counter, out);
}

// Round 2
// 64.333 us; speedup vs baseline: 5.8565x; 5.8565x over previous
//
#include <hip/hip_runtime.h>

// ---------------------------------------------------------------------------
// SNN Perceptron Equalizer (LIF recurrent net), MI355X
//
//  * xt @ W_in^T collapses to <=3 precomputed partial-dot table rows
//    P[t][seg][symbol][h]  (invalid 3rd segments are zero-filled so the hot
//    loop is branch-free).
//  * One WAVE owns one batch element; lane l holds h = 4l..4l+3 in a float4.
//    Spike masks are exchanged via __ballot (registers only) -> the 32-step
//    scan runs with NO barriers and NO LDS traffic.
//  * z @ W_rec^T is a sparse gather of pre-transposed W_rec rows (coalesced
//    float4 per lane from L2).
//  * z_sum[b,:] = 32*b_out + sum_h count[b,h] * W_out[:,h]
//  * spikerate = total_spikes / 2^25
// ---------------------------------------------------------------------------

#define T_STEPS 32
#define FDIM    41
#define HDIM    256
#define ODIM    16
#define BDIM    4096
#define MF      164

#define P_FLOATS  (32 * 3 * 16 * 256)
#define WT_FLOATS (256 * 256)

// ---------------------------------------------------------------------------
// K1: build P table (fp64 accum, W_in reused across all 16 symbols),
//     transpose W_rec, zero spike counter.
// blocks 0..95: (t,seg) P-builders; blocks 96..351: W_rec transpose.
// ---------------------------------------------------------------------------
__global__ __launch_bounds__(256) void k_prep(const float* __restrict__ emb,
                                              const float* __restrict__ W_in,
                                              const float* __restrict__ W_rec,
                                              float* __restrict__ P,
                                              float* __restrict__ WT,
                                              int* __restrict__ counter)
{
    const int bid = blockIdx.x;
    const int tid = threadIdx.x;

    if (bid < 96) {
        const int t  = bid / 3;
        const int si = bid % 3;
        const int k0   = t * MF;
        const int f    = (k0 >> 7) + si;
        const int base = f << 7;
        const int c0   = max(k0, base) - base;
        const int c1   = min(k0 + MF, base + 128) - base;
        const int len  = c1 - c0;

        if (len <= 0) {
            // invalid segment: zero-fill so k_main can read unconditionally
            #pragma unroll
            for (int s = 0; s < 16; ++s)
                P[((t * 3 + si) * 16 + s) * 256 + tid] = 0.0f;
            return;
        }

        __shared__ float emb_lds[16][128];
        for (int idx = tid; idx < 16 * 128; idx += 256) {
            const int s = idx >> 7, u = idx & 127;
            if (u < len) emb_lds[s][u] = emb[(s << 7) + c0 + u];
        }
        __syncthreads();

        const int j0 = base + c0 - k0;   // window-local start column
        double acc[16];
        #pragma unroll
        for (int s = 0; s < 16; ++s) acc[s] = 0.0;
        for (int u = 0; u < len; ++u) {
            const double w = (double)W_in[tid * MF + j0 + u];
            #pragma unroll
            for (int s = 0; s < 16; ++s)
                acc[s] += w * (double)emb_lds[s][u];
        }
        #pragma unroll
        for (int s = 0; s < 16; ++s)
            P[((t * 3 + si) * 16 + s) * 256 + tid] = (float)acc[s];
    } else {
        // transpose W_rec: WT[h][j] = W_rec[j][h]
        const int h = bid - 96;
        WT[h * 256 + tid] = W_rec[tid * 256 + h];
        if (h == 0 && tid == 0) *counter = 0;
    }
}

// ---------------------------------------------------------------------------
// K2: main LIF scan. grid = BDIM/4 = 1024 blocks, 256 threads = 4 independent
// waves; wave owns batch element b, lane l owns h = 4l..4l+3.
// ---------------------------------------------------------------------------
__global__ __launch_bounds__(256) void k_main(const int* __restrict__ x,
                                              const float* __restrict__ P,
                                              const float* __restrict__ WT,
                                              const float* __restrict__ W_out,
                                              const float* __restrict__ b_out,
                                              float* __restrict__ out,
                                              int* __restrict__ counter)
{
#pragma clang fp contract(off)
    __shared__ float cnt_lds[4][256];
    __shared__ int   red[4];

    const int tid  = threadIdx.x;
    const int lane = tid & 63;
    const int wv   = __builtin_amdgcn_readfirstlane(tid >> 6);
    const int b    = blockIdx.x * 4 + wv;

    const int*    __restrict__ xb  = x + b * FDIM;
    const float4* __restrict__ P4  = (const float4*)P;
    const float4* __restrict__ WT4 = (const float4*)WT;

    float vx = 0.f, vy = 0.f, vz = 0.f, vw = 0.f;   // membrane
    float ix = 0.f, iy = 0.f, iz = 0.f, iw = 0.f;   // synaptic current
    float rx = 0.f, ry = 0.f, rz = 0.f, rw = 0.f;   // rec term from z_{t-1}
    int   n0 = 0, n1 = 0, n2 = 0, n3 = 0;           // spike counts per h

    #pragma unroll
    for (int t = 0; t < T_STEPS; ++t) {
        const int k0 = t * MF;
        const int f0 = k0 >> 7;
        const int f2 = (f0 + 2 < FDIM) ? f0 + 2 : FDIM - 1;  // clamp (row is 0)
        const int s0 = xb[f0];
        const int s1 = xb[f0 + 1];
        const int s2 = xb[f2];

        const float4 p0 = P4[((t * 3 + 0) * 16 + s0) * 64 + lane];
        const float4 p1 = P4[((t * 3 + 1) * 16 + s1) * 64 + lane];
        const float4 p2 = P4[((t * 3 + 2) * 16 + s2) * 64 + lane];
        const float fx = (p0.x + p1.x) + p2.x;
        const float fy = (p0.y + p1.y) + p2.y;
        const float fz = (p0.z + p1.z) + p2.z;
        const float fw = (p0.w + p1.w) + p2.w;

        // LIF dynamics (fp32, contraction off; matches reference ordering)
        const float vdx = vx + 0.1f * (ix - vx);
        const float vdy = vy + 0.1f * (iy - vy);
        const float vdz = vz + 0.1f * (iz - vz);
        const float vdw = vw + 0.1f * (iw - vw);
        const float idx_ = ix * 0.8f;
        const float idy_ = iy * 0.8f;
        const float idz_ = iz * 0.8f;
        const float idw_ = iw * 0.8f;

        const bool z0 = vdx > 1.0f;
        const bool z1 = vdy > 1.0f;
        const bool z2 = vdz > 1.0f;
        const bool z3 = vdw > 1.0f;

        vx = z0 ? 0.0f : vdx;
        vy = z1 ? 0.0f : vdy;
        vz = z2 ? 0.0f : vdz;
        vw = z3 ? 0.0f : vdw;

        // i_new = (i_dec + ff) + rec(z_{t-1})
        ix = (idx_ + fx) + rx;
        iy = (idy_ + fy) + ry;
        iz = (idz_ + fz) + rz;
        iw = (idw_ + fw) + rw;

        n0 += z0; n1 += z1; n2 += z2; n3 += z3;

        // gather rec for NEXT step from this step's spikes (register masks)
        unsigned long long m0 = __ballot(z0);
        unsigned long long m1 = __ballot(z1);
        unsigned long long m2 = __ballot(z2);
        unsigned long long m3 = __ballot(z3);

        rx = 0.f; ry = 0.f; rz = 0.f; rw = 0.f;
        while (m0) {
            const int l = __builtin_ctzll(m0); m0 &= m0 - 1;
            const float4 w = WT4[(4 * l + 0) * 64 + lane];
            rx += w.x; ry += w.y; rz += w.z; rw += w.w;
        }
        while (m1) {
            const int l = __builtin_ctzll(m1); m1 &= m1 - 1;
            const float4 w = WT4[(4 * l + 1) * 64 + lane];
            rx += w.x; ry += w.y; rz += w.z; rw += w.w;
        }
        while (m2) {
            const int l = __builtin_ctzll(m2); m2 &= m2 - 1;
            const float4 w = WT4[(4 * l + 2) * 64 + lane];
            rx += w.x; ry += w.y; rz += w.z; rw += w.w;
        }
        while (m3) {
            const int l = __builtin_ctzll(m3); m3 &= m3 - 1;
            const float4 w = WT4[(4 * l + 3) * 64 + lane];
            rx += w.x; ry += w.y; rz += w.z; rw += w.w;
        }
    }

    // --- publish per-h spike counts & block spike total ---
    cnt_lds[wv][4 * lane + 0] = (float)n0;
    cnt_lds[wv][4 * lane + 1] = (float)n1;
    cnt_lds[wv][4 * lane + 2] = (float)n2;
    cnt_lds[wv][4 * lane + 3] = (float)n3;

    int myspk = n0 + n1 + n2 + n3;
    #pragma unroll
    for (int off = 32; off > 0; off >>= 1)
        myspk += __shfl_down(myspk, off, 64);
    if (lane == 0) red[wv] = myspk;

    __syncthreads();
    if (tid == 0) atomicAdd(counter, red[0] + red[1] + red[2] + red[3]);

    // --- epilogue: z_sum[b,o] = 32*b_out[o] + sum_h cnt[h]*W_out[o,h] ---
    if (lane < 16) {
        const int o = lane;
        float acc = 32.0f * b_out[o];
        const float* __restrict__ wo = W_out + o * 256;
        const float* __restrict__ cl = cnt_lds[wv];
        for (int h = 0; h < 256; ++h)
            acc += cl[h] * wo[h];
        out[b * ODIM + o] = acc;
    }
}

// ---------------------------------------------------------------------------
// K3: spikerate = count / 2^25 (exact in fp32 since count < 2^24)
// ---------------------------------------------------------------------------
__global__ void k_fin(const int* __restrict__ counter, float* __restrict__ out)
{
    out[BDIM * ODIM] = (float)(*counter) * (1.0f / 33554432.0f);
}

// ---------------------------------------------------------------------------
extern "C" void kernel_launch(void* const* d_in, const int* in_sizes, int n_in,
                              void* d_out, int out_size, void* d_ws, size_t ws_size,
                              hipStream_t stream)
{
    const int*   x     = (const int*)  d_in[0];
    const float* emb   = (const float*)d_in[1];
    const float* W_in  = (const float*)d_in[2];
    const float* W_rec = (const float*)d_in[3];
    const float* W_out = (const float*)d_in[4];
    const float* b_out = (const float*)d_in[5];
    float* out = (float*)d_out;

    float* P       = (float*)d_ws;
    float* WT      = P + P_FLOATS;
    int*   counter = (int*)(WT + WT_FLOATS);

    k_prep<<<96 + 256, 256, 0, stream>>>(emb, W_in, W_rec, P, WT, counter);
    k_main<<<BDIM / 4, 256, 0, stream>>>(x, P, WT, W_out, b_out, out, counter);
    k_fin<<<1, 1, 0, stream>>>(counter, out);
}

// Round 3
// 59.119 us; speedup vs baseline: 6.3731x; 1.0882x over previous
//
#include <hip/hip_runtime.h>

// ---------------------------------------------------------------------------
// SNN Perceptron Equalizer (LIF recurrent net), MI355X
//
//  * xt @ W_in^T collapses to <=3 precomputed partial-dot table rows
//    P[t][seg][symbol][h]  (invalid 3rd segments zero-filled -> branch-free).
//  * One WAVE owns one batch element; lane l holds h = 4l..4l+3 in a float4.
//    Spike masks are exchanged via __ballot (registers only) -> no barriers,
//    no LDS in the 32-step scan.
//  * The P-load addresses depend only on the input symbols, NOT on the
//    recurrent state -> depth-4 explicit software pipeline (register ring
//    pf[4][3]) keeps ~12 L2 loads in flight per wave and hides L2 latency.
//  * z @ W_rec^T is a sparse gather of pre-transposed W_rec rows (rare).
//  * z_sum[b,:] = 32*b_out + sum_h count[b,h] * W_out[:,h]
//  * spikerate = total_spikes / 2^25
// ---------------------------------------------------------------------------

#define T_STEPS 32
#define FDIM    41
#define HDIM    256
#define ODIM    16
#define BDIM    4096
#define MF      164

#define P_FLOATS  (32 * 3 * 16 * 256)
#define WT_FLOATS (256 * 256)

// ---------------------------------------------------------------------------
// K1: build P table (fp64 accum, W_in reused across all 16 symbols),
//     transpose W_rec, zero spike counter.
// blocks 0..95: (t,seg) P-builders; blocks 96..351: W_rec transpose.
// ---------------------------------------------------------------------------
__global__ __launch_bounds__(256) void k_prep(const float* __restrict__ emb,
                                              const float* __restrict__ W_in,
                                              const float* __restrict__ W_rec,
                                              float* __restrict__ P,
                                              float* __restrict__ WT,
                                              int* __restrict__ counter)
{
    const int bid = blockIdx.x;
    const int tid = threadIdx.x;

    if (bid < 96) {
        const int t  = bid / 3;
        const int si = bid % 3;
        const int k0   = t * MF;
        const int f    = (k0 >> 7) + si;
        const int base = f << 7;
        const int c0   = max(k0, base) - base;
        const int c1   = min(k0 + MF, base + 128) - base;
        const int len  = c1 - c0;

        if (len <= 0) {
            // invalid segment: zero-fill so k_main can read unconditionally
            #pragma unroll
            for (int s = 0; s < 16; ++s)
                P[((t * 3 + si) * 16 + s) * 256 + tid] = 0.0f;
            return;
        }

        __shared__ float emb_lds[16][128];
        for (int idx = tid; idx < 16 * 128; idx += 256) {
            const int s = idx >> 7, u = idx & 127;
            if (u < len) emb_lds[s][u] = emb[(s << 7) + c0 + u];
        }
        __syncthreads();

        const int j0 = base + c0 - k0;   // window-local start column
        double acc[16];
        #pragma unroll
        for (int s = 0; s < 16; ++s) acc[s] = 0.0;
        for (int u = 0; u < len; ++u) {
            const double w = (double)W_in[tid * MF + j0 + u];
            #pragma unroll
            for (int s = 0; s < 16; ++s)
                acc[s] += w * (double)emb_lds[s][u];
        }
        #pragma unroll
        for (int s = 0; s < 16; ++s)
            P[((t * 3 + si) * 16 + s) * 256 + tid] = (float)acc[s];
    } else {
        // transpose W_rec: WT[h][j] = W_rec[j][h]
        const int h = bid - 96;
        WT[h * 256 + tid] = W_rec[tid * 256 + h];
        if (h == 0 && tid == 0) *counter = 0;
    }
}

// ---------------------------------------------------------------------------
// K2: main LIF scan. grid = BDIM/4 = 1024 blocks, 256 threads = 4 independent
// waves; wave owns batch element b, lane l owns h = 4l..4l+3.
// Depth-4 register-ring prefetch of the feedforward table rows.
// ---------------------------------------------------------------------------
__global__ __launch_bounds__(256) void k_main(const int* __restrict__ x,
                                              const float* __restrict__ P,
                                              const float* __restrict__ WT,
                                              const float* __restrict__ W_out,
                                              const float* __restrict__ b_out,
                                              float* __restrict__ out,
                                              int* __restrict__ counter)
{
#pragma clang fp contract(off)
    __shared__ float cnt_lds[4][256];
    __shared__ int   red[4];

    const int tid  = threadIdx.x;
    const int lane = tid & 63;
    const int wv   = __builtin_amdgcn_readfirstlane(tid >> 6);
    const int b    = blockIdx.x * 4 + wv;

    const int*    __restrict__ xb  = x + b * FDIM;
    const float4* __restrict__ P4  = (const float4*)P;
    const float4* __restrict__ WT4 = (const float4*)WT;

    // all symbols into SGPRs up front (uniform per wave)
    int sym[FDIM];
    #pragma unroll
    for (int f = 0; f < FDIM; ++f)
        sym[f] = __builtin_amdgcn_readfirstlane(xb[f]);

    float vx = 0.f, vy = 0.f, vz = 0.f, vw = 0.f;   // membrane
    float ix = 0.f, iy = 0.f, iz = 0.f, iw = 0.f;   // synaptic current
    int   n0 = 0, n1 = 0, n2 = 0, n3 = 0;           // spike counts per h
    unsigned long long m0 = 0, m1 = 0, m2 = 0, m3 = 0;  // z_{t-1} masks

    float4 pf[4][3];                                 // prefetch ring

    #define ISSUE(T, SLOT)                                                   \
        do {                                                                 \
            const int f0_ = ((T) * MF) >> 7;                                 \
            const int f2_ = (f0_ + 2 < FDIM) ? f0_ + 2 : FDIM - 1;           \
            pf[SLOT][0] = P4[(((T) * 3 + 0) * 16 + sym[f0_]) * 64 + lane];   \
            pf[SLOT][1] = P4[(((T) * 3 + 1) * 16 + sym[f0_ + 1]) * 64 + lane];\
            pf[SLOT][2] = P4[(((T) * 3 + 2) * 16 + sym[f2_]) * 64 + lane];   \
        } while (0)

    #pragma unroll
    for (int t = 0; t < 4; ++t) ISSUE(t, t);

    #pragma unroll
    for (int t = 0; t < T_STEPS; ++t) {
        const int slot = t & 3;

        // consume prefetched feedforward rows
        const float4 p0 = pf[slot][0];
        const float4 p1 = pf[slot][1];
        const float4 p2 = pf[slot][2];

        // immediately re-issue this slot for t+4
        if (t + 4 < T_STEPS) ISSUE(t + 4, slot);

        const float fx = (p0.x + p1.x) + p2.x;
        const float fy = (p0.y + p1.y) + p2.y;
        const float fz = (p0.z + p1.z) + p2.z;
        const float fw = (p0.w + p1.w) + p2.w;

        // sparse recurrent gather from z_{t-1} (masks from previous iter)
        float rx = 0.f, ry = 0.f, rz = 0.f, rw = 0.f;
        while (m0) {
            const int l = __builtin_ctzll(m0); m0 &= m0 - 1;
            const float4 w = WT4[(4 * l + 0) * 64 + lane];
            rx += w.x; ry += w.y; rz += w.z; rw += w.w;
        }
        while (m1) {
            const int l = __builtin_ctzll(m1); m1 &= m1 - 1;
            const float4 w = WT4[(4 * l + 1) * 64 + lane];
            rx += w.x; ry += w.y; rz += w.z; rw += w.w;
        }
        while (m2) {
            const int l = __builtin_ctzll(m2); m2 &= m2 - 1;
            const float4 w = WT4[(4 * l + 2) * 64 + lane];
            rx += w.x; ry += w.y; rz += w.z; rw += w.w;
        }
        while (m3) {
            const int l = __builtin_ctzll(m3); m3 &= m3 - 1;
            const float4 w = WT4[(4 * l + 3) * 64 + lane];
            rx += w.x; ry += w.y; rz += w.z; rw += w.w;
        }

        // LIF dynamics (fp32, contraction off; matches reference ordering)
        const float vdx = vx + 0.1f * (ix - vx);
        const float vdy = vy + 0.1f * (iy - vy);
        const float vdz = vz + 0.1f * (iz - vz);
        const float vdw = vw + 0.1f * (iw - vw);
        const float idx_ = ix * 0.8f;
        const float idy_ = iy * 0.8f;
        const float idz_ = iz * 0.8f;
        const float idw_ = iw * 0.8f;

        const bool z0 = vdx > 1.0f;
        const bool z1 = vdy > 1.0f;
        const bool z2 = vdz > 1.0f;
        const bool z3 = vdw > 1.0f;

        vx = z0 ? 0.0f : vdx;
        vy = z1 ? 0.0f : vdy;
        vz = z2 ? 0.0f : vdz;
        vw = z3 ? 0.0f : vdw;

        ix = (idx_ + fx) + rx;
        iy = (idy_ + fy) + ry;
        iz = (idz_ + fz) + rz;
        iw = (idw_ + fw) + rw;

        n0 += z0; n1 += z1; n2 += z2; n3 += z3;

        m0 = __ballot(z0);
        m1 = __ballot(z1);
        m2 = __ballot(z2);
        m3 = __ballot(z3);
    }
    #undef ISSUE

    // --- publish per-h spike counts & block spike total ---
    cnt_lds[wv][4 * lane + 0] = (float)n0;
    cnt_lds[wv][4 * lane + 1] = (float)n1;
    cnt_lds[wv][4 * lane + 2] = (float)n2;
    cnt_lds[wv][4 * lane + 3] = (float)n3;

    int myspk = n0 + n1 + n2 + n3;
    #pragma unroll
    for (int off = 32; off > 0; off >>= 1)
        myspk += __shfl_down(myspk, off, 64);
    if (lane == 0) red[wv] = myspk;

    __syncthreads();
    if (tid == 0) atomicAdd(counter, red[0] + red[1] + red[2] + red[3]);

    // --- epilogue: z_sum[b,o] = 32*b_out[o] + sum_h cnt[h]*W_out[o,h] ---
    // lane = (q,o): o = lane&15, quarter q = lane>>4; 64-h partial per lane,
    // then reduce across the 4 quarters with two shuffles.
    {
        const int o = lane & 15;
        const int q = lane >> 4;
        const float* __restrict__ wo = W_out + o * 256 + q * 64;
        const float* __restrict__ cl = cnt_lds[wv] + q * 64;
        float acc = 0.0f;
        #pragma unroll 8
        for (int h = 0; h < 64; ++h)
            acc += cl[h] * wo[h];
        acc += __shfl_down(acc, 16, 64);
        acc += __shfl_down(acc, 32, 64);
        if (q == 0)
            out[b * ODIM + o] = 32.0f * b_out[o] + acc;
    }
}

// ---------------------------------------------------------------------------
// K3: spikerate = count / 2^25 (exact in fp32 since count < 2^24)
// ---------------------------------------------------------------------------
__global__ void k_fin(const int* __restrict__ counter, float* __restrict__ out)
{
    out[BDIM * ODIM] = (float)(*counter) * (1.0f / 33554432.0f);
}

// ---------------------------------------------------------------------------
extern "C" void kernel_launch(void* const* d_in, const int* in_sizes, int n_in,
                              void* d_out, int out_size, void* d_ws, size_t ws_size,
                              hipStream_t stream)
{
    const int*   x     = (const int*)  d_in[0];
    const float* emb   = (const float*)d_in[1];
    const float* W_in  = (const float*)d_in[2];
    const float* W_rec = (const float*)d_in[3];
    const float* W_out = (const float*)d_in[4];
    const float* b_out = (const float*)d_in[5];
    float* out = (float*)d_out;

    float* P       = (float*)d_ws;
    float* WT      = P + P_FLOATS;
    int*   counter = (int*)(WT + WT_FLOATS);

    k_prep<<<96 + 256, 256, 0, stream>>>(emb, W_in, W_rec, P, WT, counter);
    k_main<<<BDIM / 4, 256, 0, stream>>>(x, P, WT, W_out, b_out, out, counter);
    k_fin<<<1, 1, 0, stream>>>(counter, out);
}